// Round 3
// baseline (228.531 us; speedup 1.0000x reference)
//
#include <hip/hip_runtime.h>

#define NC 64      // channels / signal dim
#define NA 512     // dictionary atoms
#define KS 5       // sparsity

// ---- workspace layout in FLOATS (accum as double at 8B-aligned tail) ----
#define WS_DN   0        // Dn  [NC][NA]
#define WS_DNT  32768    // DnT [NA][NC]
#define WS_G    65536    // G   [NA][NA]
#define WS_ACCF 327680   // double accumulator lives here (byte off 1310720)

// out layout (FLOAT32): z_dl[2097152] | loss[1] | support[163840] | coeffs[163840]
#define OUT_LOSS 2097152
#define OUT_SUP  2097153
#define OUT_COF  2260993

__global__ void norm_kernel(const float* __restrict__ D, float* __restrict__ Dn,
                            float* __restrict__ DnT) {
  int n = blockIdx.x * 64 + threadIdx.x;
  float s = 0.f;
  for (int c = 0; c < NC; ++c) {
    float v = D[c * NA + n];
    s += v * v;
  }
  float den = fmaxf(sqrtf(s), 1e-10f);
  for (int c = 0; c < NC; ++c) {
    float v = D[c * NA + n] / den;      // f32 true division, mirrors ref
    Dn[c * NA + n]  = v;
    DnT[n * NC + c] = v;
  }
}

__global__ void gram_kernel(const float* __restrict__ Dn,
                            float* __restrict__ G, double* __restrict__ accum) {
  __shared__ float col[NC];
  int i = blockIdx.x, t = threadIdx.x;
  if (t < NC) col[t] = Dn[t * NA + i];
  if (i == 0 && t == 0) *accum = 0.0;
  __syncthreads();
  float s = 0.f;
#pragma unroll
  for (int c = 0; c < NC; ++c) s += col[c] * Dn[c * NA + t];
  G[(size_t)i * NA + t] = s;
}

// One OMP iteration for BOTH of the wave's signals in lockstep (dual-ILP:
// every latency chain -- argmax butterfly, Gc L2 loads, Cholesky/solve
// recurrences -- has two independent instances in flight).  All private
// indices are literal after unroll -> SROA keeps state in VGPRs.
// Lane owns atom pairs: slot s (0..7) <-> atom a = (s>>1)*128 + 2*lane + (s&1).
// Lo = strictly-lower off-diagonals of L (diag never read; rd = 1/diag).
// State diet vs R1/R2 (anti-spill): hbI[] deleted -- h_bar at the support is
// re-read from the immutable LDS park during the solve (bit-identical values);
// both 8-bit masks live in ONE register (bit si*8+slot).
template<int KK>
__device__ __forceinline__ void omp_step2(
    const int lane, const float* __restrict__ G,
    const float* __restrict__ park,
    float (&h8)[2][8], unsigned &msk, int (&I)[2][KS],
    float (&Lo)[2][10], float (&rd)[2][KS], float (&gam)[2][KS]) {
  // ---- dual argmax |h|*mask; ascending-atom scan, strict '>' = first-occurrence
  float bv[2]; int bn[2];
#pragma unroll
  for (int si = 0; si < 2; ++si) {
    bv[si] = -1.f; bn[si] = 0;
#pragma unroll
    for (int s = 0; s < 8; ++s) {
      int a = ((s >> 1) << 7) + 2 * lane + (s & 1);
      float v = ((msk >> (si * 8 + s)) & 1u) ? fabsf(h8[si][s]) : 0.f;
      if (v > bv[si]) { bv[si] = v; bn[si] = a; }
    }
  }
#pragma unroll
  for (int off = 1; off < 64; off <<= 1) {
#pragma unroll
    for (int si = 0; si < 2; ++si) {
      float ov = __shfl_xor(bv[si], off);
      int   on = __shfl_xor(bn[si], off);
      if (ov > bv[si] || (ov == bv[si] && on < bn[si])) { bv[si] = ov; bn[si] = on; }
    }
  }
#pragma unroll
  for (int si = 0; si < 2; ++si) {
    const int idx = bn[si];                          // wave-uniform
    if (((idx & 127) >> 1) == lane)
      msk &= ~(1u << (si * 8 + (((idx >> 7) << 1) | (idx & 1))));
    I[si][KK] = idx;
  }

  // ---- dual Cholesky rank-1 extension (replicated on all lanes)
  if constexpr (KK == 0) {
#pragma unroll
    for (int si = 0; si < 2; ++si) rd[si][0] = 1.f;
  } else {
    float Gc[2][KK];
#pragma unroll
    for (int si = 0; si < 2; ++si)
#pragma unroll
      for (int j = 0; j < KK; ++j)
        Gc[si][j] = G[(size_t)I[si][j] * NA + I[si][KK]];
    float w_[2][KK];
#pragma unroll
    for (int i = 0; i < KK; ++i)
#pragma unroll
      for (int si = 0; si < 2; ++si) {
        float ssum = Gc[si][i];
#pragma unroll
        for (int j = 0; j < i; ++j) ssum -= Lo[si][i*(i-1)/2 + j] * w_[si][j];
        w_[si][i] = ssum * rd[si][i];
      }
#pragma unroll
    for (int si = 0; si < 2; ++si) {
      float ww = 0.f;
#pragma unroll
      for (int i = 0; i < KK; ++i) ww += w_[si][i] * w_[si][i];
      float corner = sqrtf(fmaxf(1.f - ww, 1e-12f));
#pragma unroll
      for (int j = 0; j < KK; ++j) Lo[si][KK*(KK-1)/2 + j] = w_[si][j];
      rd[si][KK] = 1.f / corner;
    }
  }

  // ---- dual cho_solve((L, lower), h_bar[I]) at size KK+1
  // h_bar values come from the immutable LDS park (uniform-index broadcast)
  float y[2][KK + 1];
#pragma unroll
  for (int i = 0; i <= KK; ++i)
#pragma unroll
    for (int si = 0; si < 2; ++si) {
      float b_ = park[si * NA + I[si][i]];
#pragma unroll
      for (int j = 0; j < i; ++j) b_ -= Lo[si][i*(i-1)/2 + j] * y[si][j];
      y[si][i] = b_ * rd[si][i];
    }
#pragma unroll
  for (int i = KK; i >= 0; --i)
#pragma unroll
    for (int si = 0; si < 2; ++si) {
      float g_ = y[si][i];
#pragma unroll
      for (int j = i + 1; j <= KK; ++j) g_ -= Lo[si][j*(j-1)/2 + i] * gam[si][j];
      gam[si][i] = g_ * rd[si][i];
    }

  // ---- dual h refresh: h = h_bar - sum_j gam_j * G[I_j]
  if constexpr (KK < 4) {
    const float2* pk2 = (const float2*)park;
#pragma unroll
    for (int si = 0; si < 2; ++si)
#pragma unroll
      for (int i = 0; i < 4; ++i) {
        float2 hv = pk2[si * 256 + (i << 6) + lane];
        h8[si][i * 2] = hv.x; h8[si][i * 2 + 1] = hv.y;
      }
#pragma unroll
    for (int j = 0; j <= KK; ++j)
#pragma unroll
      for (int si = 0; si < 2; ++si) {
        const float2* g2 = (const float2*)(G + (size_t)I[si][j] * NA);
        const float gj = gam[si][j];
#pragma unroll
        for (int i = 0; i < 4; ++i) {
          float2 g = g2[(i << 6) + lane];
          h8[si][i * 2]     -= gj * g.x;
          h8[si][i * 2 + 1] -= gj * g.y;
        }
      }
  }
}

// 8 signals per block (2 per wave, processed in LOCKSTEP), grid 4096.
// LDS: 16 KB stage/park union + 2 KB xsz -> ~18.4 KB -> 8 blocks/CU by LDS.
// __launch_bounds__(256, 2): the R0-proven configuration under which the
// allocator allocates to pressure (no 8-wave squeeze).  R1's (256,4) and
// R2's waves_per_eu(4,4) both left VGPR at 64 WITH scratch spills
// (WRITE_SIZE 169/55 MB vs 10 MB algorithmic).  Dual state is ~95 regs
// after the hbI/msk diet -> expect ~96-128 VGPR, 4 waves/SIMD, zero spill.
__global__ __launch_bounds__(256, 2) void omp_kernel(
    const float* __restrict__ z, const float* __restrict__ Dn,
    const float* __restrict__ DnT, const float* __restrict__ G,
    float* __restrict__ out, double* __restrict__ accum) {
  __shared__ __align__(16) float buf[8 * NA];  // 16 KB: Dn stage, then h_bar park
  __shared__ float xsz[8 * NC];      // 2 KB: xs[s][c] first, zout[c][s] later
  __shared__ double wsq[8];
  const int t = threadIdx.x, lane = t & 63, wv = t >> 6;
  const int m0 = blockIdx.x * 8;
  const int bh = m0 >> 6, b = bh >> 6, h = bh & 63, w0 = m0 & 63;
  const size_t zbase = (size_t)b * 262144 + (size_t)h * 64 + w0;

  // prefetch chunk 0 of Dn immediately (hides under signal load + xsz barrier)
  const float4* D4 = (const float4*)Dn;
  float4 r0 = D4[t], r1 = D4[256 + t], r2 = D4[512 + t], r3 = D4[768 + t];

  // load 8 signals coalesced into xs (xsz[s*64+c])
  for (int j = t; j < 8 * NC; j += 256) {
    int c = j >> 3, s = j & 7;
    xsz[s * NC + c] = z[zbase + (size_t)c * 4096 + s];
  }
  __syncthreads();
  // per-lane copy: lane holds channel=lane value of its wave's two signals
  const float xf0 = xsz[(wv * 2 + 0) * NC + lane];
  const float xf1 = xsz[(wv * 2 + 1) * NC + lane];
  // xsz free from here (zout reuses it)

  float h8[2][8];                    // h_bar stays in regs as h(0)

  // ---- phase 1: f32 h_bar GEMM, Dn staged through LDS in 8-row chunks,
  // next chunk prefetched into regs BEFORE compute (issue-early/write-late)
  {
    float acc[2][8];
#pragma unroll
    for (int si = 0; si < 2; ++si)
#pragma unroll
      for (int i = 0; i < 8; ++i) acc[si][i] = 0.f;

    float4* st4 = (float4*)buf;
    for (int ch = 0; ch < 8; ++ch) {
      if (ch) __syncthreads();             // previous chunk fully consumed
      st4[t] = r0; st4[256 + t] = r1; st4[512 + t] = r2; st4[768 + t] = r3;
      __syncthreads();
      if (ch < 7) {                        // prefetch next chunk; lands during
        const float4* Dx = D4 + (ch + 1) * 1024;   // the 8 c8-iterations below
        r0 = Dx[t]; r1 = Dx[256 + t]; r2 = Dx[512 + t]; r3 = Dx[768 + t];
      }
#pragma unroll
      for (int c8 = 0; c8 < 8; ++c8) {
        const int c = ch * 8 + c8;
        const float x0 = __shfl(xf0, c);
        const float x1 = __shfl(xf1, c);
        const float2* row2 = (const float2*)(buf + c8 * NA);
#pragma unroll
        for (int i = 0; i < 4; ++i) {
          float2 dv = row2[(i << 6) + lane];
          acc[0][i * 2] += x0 * dv.x; acc[0][i * 2 + 1] += x0 * dv.y;
          acc[1][i * 2] += x1 * dv.x; acc[1][i * 2 + 1] += x1 * dv.y;
        }
      }
    }
    __syncthreads();                       // all waves done reading stage
    // park h_bar into the same 16 KB (per-wave region) and keep regs copy
    float2* park2 = (float2*)buf;
#pragma unroll
    for (int si = 0; si < 2; ++si)
#pragma unroll
      for (int i = 0; i < 4; ++i) {
        float2 v; v.x = acc[si][i * 2]; v.y = acc[si][i * 2 + 1];
        park2[(size_t)(wv * 2 + si) * 256 + (i << 6) + lane] = v;
        h8[si][i * 2] = v.x; h8[si][i * 2 + 1] = v.y;
      }
  }

  // ---- phase 2: OMP, both of the wave's signals interleaved
  const float* park = buf + (size_t)(wv * 2) * NA;
  unsigned msk = 0xFFFFu;            // bits [7:0] = signal 0, [15:8] = signal 1
  int I[2][KS];
  float Lo[2][10], rd[2][KS], gam[2][KS];

  omp_step2<0>(lane, G, park, h8, msk, I, Lo, rd, gam);
  omp_step2<1>(lane, G, park, h8, msk, I, Lo, rd, gam);
  omp_step2<2>(lane, G, park, h8, msk, I, Lo, rd, gam);
  omp_step2<3>(lane, G, park, h8, msk, I, Lo, rd, gam);
  omp_step2<4>(lane, G, park, h8, msk, I, Lo, rd, gam);

  // ---- dual epilogue
  float rr[2] = {0.f, 0.f};
#pragma unroll
  for (int j = 0; j < KS; ++j)
#pragma unroll
    for (int si = 0; si < 2; ++si)
      rr[si] += gam[si][j] * DnT[(size_t)I[si][j] * NC + lane];
  const float e[2] = {xf0, xf1};
  double sq[2];
#pragma unroll
  for (int si = 0; si < 2; ++si) {
    const int sig = wv * 2 + si;
    const float d = rr[si] - e[si];              // z_dl - z_e
    xsz[lane * 8 + sig] = e[si] + d;             // zout[c=lane][s=sig]
    sq[si] = (double)d * (double)d;
  }
#pragma unroll
  for (int off = 1; off < 64; off <<= 1)
#pragma unroll
    for (int si = 0; si < 2; ++si)
      sq[si] += __shfl_xor(sq[si], off);
  if (lane == 0) { wsq[wv * 2] = sq[0]; wsq[wv * 2 + 1] = sq[1]; }

  // support / coeffs: constant-index selection chains only
  if (lane < KS) {
#pragma unroll
    for (int si = 0; si < 2; ++si) {
      int   iv = I[si][0];
      float gv = gam[si][0];
      if (lane == 1) { iv = I[si][1]; gv = gam[si][1]; }
      if (lane == 2) { iv = I[si][2]; gv = gam[si][2]; }
      if (lane == 3) { iv = I[si][3]; gv = gam[si][3]; }
      if (lane == 4) { iv = I[si][4]; gv = gam[si][4]; }
      const int m = m0 + wv * 2 + si;
      out[OUT_SUP + (size_t)m * KS + lane] = (float)iv;
      out[OUT_COF + (size_t)m * KS + lane] = gv;
    }
  }

  __syncthreads();
  // coalesced z_dl store from zout (xsz[c*8+s])
  for (int j = t; j < 8 * NC; j += 256) {
    int c = j >> 3, s = j & 7;
    out[zbase + (size_t)c * 4096 + s] = xsz[j];
  }
  if (t == 0) {
    double ssum = 0.0;
#pragma unroll
    for (int i = 0; i < 8; ++i) ssum += wsq[i];
    atomicAdd(accum, ssum);
  }
}

__global__ void final_kernel(const double* __restrict__ accum, float* __restrict__ out) {
  double mse = *accum / 2097152.0;
  out[OUT_LOSS] = (float)(mse + 0.25 * mse);
}

extern "C" void kernel_launch(void* const* d_in, const int* in_sizes, int n_in,
                              void* d_out, int out_size, void* d_ws, size_t ws_size,
                              hipStream_t stream) {
  const float* z_e = (const float*)d_in[0];
  const float* dic = (const float*)d_in[1];
  float* out = (float*)d_out;
  float* ws = (float*)d_ws;
  float* Dn   = ws + WS_DN;
  float* DnT  = ws + WS_DNT;
  float* G    = ws + WS_G;
  double* accu = (double*)(ws + WS_ACCF);

  hipLaunchKernelGGL(norm_kernel,  dim3(8),    dim3(64),  0, stream, dic, Dn, DnT);
  hipLaunchKernelGGL(gram_kernel,  dim3(NA),   dim3(NA),  0, stream, Dn, G, accu);
  hipLaunchKernelGGL(omp_kernel,   dim3(4096), dim3(256), 0, stream,
                     z_e, Dn, DnT, G, out, accu);
  hipLaunchKernelGGL(final_kernel, dim3(1),    dim3(1),   0, stream, accu, out);
}

// Round 4
// 171.591 us; speedup vs baseline: 1.3318x; 1.3318x over previous
//
#include <hip/hip_runtime.h>

#define NC 64      // channels / signal dim
#define NA 512     // dictionary atoms
#define KS 5       // sparsity

// ---- workspace layout in FLOATS (accum as double at 8B-aligned tail) ----
#define WS_DN   0        // Dn  [NC][NA]
#define WS_DNT  32768    // DnT [NA][NC]
#define WS_G    65536    // G   [NA][NA]
#define WS_ACCF 327680   // double accumulator lives here (byte off 1310720)

// out layout (FLOAT32): z_dl[2097152] | loss[1] | support[163840] | coeffs[163840]
#define OUT_LOSS 2097152
#define OUT_SUP  2097153
#define OUT_COF  2260993

__global__ void norm_kernel(const float* __restrict__ D, float* __restrict__ Dn,
                            float* __restrict__ DnT) {
  int n = blockIdx.x * 64 + threadIdx.x;
  float s = 0.f;
  for (int c = 0; c < NC; ++c) {
    float v = D[c * NA + n];
    s += v * v;
  }
  float den = fmaxf(sqrtf(s), 1e-10f);
  for (int c = 0; c < NC; ++c) {
    float v = D[c * NA + n] / den;      // f32 true division, mirrors ref
    Dn[c * NA + n]  = v;
    DnT[n * NC + c] = v;
  }
}

__global__ void gram_kernel(const float* __restrict__ Dn,
                            float* __restrict__ G, double* __restrict__ accum) {
  __shared__ float col[NC];
  int i = blockIdx.x, t = threadIdx.x;
  if (t < NC) col[t] = Dn[t * NA + i];
  if (i == 0 && t == 0) *accum = 0.0;
  __syncthreads();
  float s = 0.f;
#pragma unroll
  for (int c = 0; c < NC; ++c) s += col[c] * Dn[c * NA + t];
  G[(size_t)i * NA + t] = s;
}

// One OMP iteration, HALF-WAVE parallel: lanes 0-31 run one signal, lanes
// 32-63 the other, in the SAME instruction stream.  Dual-signal ILP with
// SINGULAR per-thread state (~60-75 regs peak -- the R0-proven no-spill
// regime; R1/R2/R3 showed register-replicated dual state spills at any
// launch-bounds setting).  The Cholesky/solve was lane-replicated anyway,
// so 32-lane replication per half is free; butterfly is 5 stages (off<=16
// stays within a half).
// Half-lane hl owns 16 atoms: slot s (0..15) <-> a = (s>>1)*64 + 2*hl + (s&1).
// Lo = strictly-lower off-diagonals of L (diag never read; rd = 1/diag).
// h_bar at the support is re-read from the immutable LDS park (bit-identical).
template<int KK>
__device__ __forceinline__ void omp_stepH(
    const int hl, const float* __restrict__ G,
    const float* __restrict__ parkS,
    float (&h16)[16], unsigned &msk, int (&I)[KS],
    float (&Lo)[10], float (&rd)[KS], float (&gam)[KS]) {
  // ---- argmax |h|*mask; ascending-atom scan, strict '>' = first-occurrence
  float bv = -1.f; int bn = 0;
#pragma unroll
  for (int s = 0; s < 16; ++s) {
    int a = ((s >> 1) << 6) + 2 * hl + (s & 1);
    float v = ((msk >> s) & 1u) ? fabsf(h16[s]) : 0.f;
    if (v > bv) { bv = v; bn = a; }
  }
#pragma unroll
  for (int off = 1; off < 32; off <<= 1) {   // within-half butterfly
    float ov = __shfl_xor(bv, off);
    int   on = __shfl_xor(bn, off);
    if (ov > bv || (ov == bv && on < bn)) { bv = ov; bn = on; }
  }
  const int idx = bn;                        // half-uniform
  if (((idx & 63) >> 1) == hl)
    msk &= ~(1u << (((idx >> 6) << 1) | (idx & 1)));
  I[KK] = idx;

  // ---- Cholesky rank-1 extension (replicated within the half)
  if constexpr (KK == 0) {
    rd[0] = 1.f;
  } else {
    float Gc[KK], w_[KK];
#pragma unroll
    for (int j = 0; j < KK; ++j) Gc[j] = G[(size_t)I[j] * NA + idx];
#pragma unroll
    for (int i = 0; i < KK; ++i) {
      float ssum = Gc[i];
#pragma unroll
      for (int j = 0; j < i; ++j) ssum -= Lo[i*(i-1)/2 + j] * w_[j];
      w_[i] = ssum * rd[i];
    }
    float ww = 0.f;
#pragma unroll
    for (int i = 0; i < KK; ++i) ww += w_[i] * w_[i];
    float corner = sqrtf(fmaxf(1.f - ww, 1e-12f));
#pragma unroll
    for (int j = 0; j < KK; ++j) Lo[KK*(KK-1)/2 + j] = w_[j];
    rd[KK] = 1.f / corner;
  }

  // ---- cho_solve((L, lower), h_bar[I]) at size KK+1 (park broadcast reads)
  float y[KK + 1];
#pragma unroll
  for (int i = 0; i <= KK; ++i) {
    float b_ = parkS[I[i]];
#pragma unroll
    for (int j = 0; j < i; ++j) b_ -= Lo[i*(i-1)/2 + j] * y[j];
    y[i] = b_ * rd[i];
  }
#pragma unroll
  for (int i = KK; i >= 0; --i) {
    float g_ = y[i];
#pragma unroll
    for (int j = i + 1; j <= KK; ++j) g_ -= Lo[j*(j-1)/2 + i] * gam[j];
    gam[i] = g_ * rd[i];
  }

  // ---- h refresh: h = h_bar - sum_j gam_j * G[I_j]
  if constexpr (KK < 4) {
    const float2* pk2 = (const float2*)parkS;
#pragma unroll
    for (int i = 0; i < 8; ++i) {
      float2 hv = pk2[(i << 5) + hl];
      h16[i * 2] = hv.x; h16[i * 2 + 1] = hv.y;
    }
#pragma unroll
    for (int j = 0; j <= KK; ++j) {
      const float2* g2 = (const float2*)(G + (size_t)I[j] * NA);
      const float gj = gam[j];
#pragma unroll
      for (int i = 0; i < 8; ++i) {
        float2 g = g2[(i << 5) + hl];
        h16[i * 2]     -= gj * g.x;
        h16[i * 2 + 1] -= gj * g.y;
      }
    }
  }
}

// 8 signals per block (2 per wave, one per 32-lane HALF), grid 4096.
// LDS: 16 KB stage/park union + 2 KB xsz -> ~18.4 KB -> 8 blocks/CU by LDS.
// __launch_bounds__(256, 2): R0-proven; singular per-thread state ~75 regs
// peak -> expect ~72-84 VGPR, zero spill.
__global__ __launch_bounds__(256, 2) void omp_kernel(
    const float* __restrict__ z, const float* __restrict__ Dn,
    const float* __restrict__ DnT, const float* __restrict__ G,
    float* __restrict__ out, double* __restrict__ accum) {
  __shared__ __align__(16) float buf[8 * NA];  // 16 KB: Dn stage, then h_bar park
  __shared__ float xsz[8 * NC];      // 2 KB: xs[s][c] first, zout[c][s] later
  __shared__ double wsq[8];
  const int t = threadIdx.x, lane = t & 63, wv = t >> 6;
  const int hl = lane & 31;
  const int m0 = blockIdx.x * 8;
  const int bh = m0 >> 6, b = bh >> 6, h = bh & 63, w0 = m0 & 63;
  const size_t zbase = (size_t)b * 262144 + (size_t)h * 64 + w0;

  // prefetch chunk 0 of Dn immediately (hides under signal load + xsz barrier)
  const float4* D4 = (const float4*)Dn;
  float4 r0 = D4[t], r1 = D4[256 + t], r2 = D4[512 + t], r3 = D4[768 + t];

  // load 8 signals coalesced into xs (xsz[s*64+c])
  for (int j = t; j < 8 * NC; j += 256) {
    int c = j >> 3, s = j & 7;
    xsz[s * NC + c] = z[zbase + (size_t)c * 4096 + s];
  }
  __syncthreads();
  // per-lane copies for phase 1 (channel = lane of the wave's two signals)
  const float xf0 = xsz[(wv * 2 + 0) * NC + lane];
  const float xf1 = xsz[(wv * 2 + 1) * NC + lane];
  // per-half copies for the epilogue: this half's signal, channels hl & hl+32
  const int sig = wv * 2 + (lane >> 5);
  const float xfa = xsz[sig * NC + hl];
  const float xfb = xsz[sig * NC + hl + 32];
  // xsz free from here (zout reuses it)

  // ---- phase 1: f32 h_bar GEMM, Dn staged through LDS in 8-row chunks,
  // next chunk prefetched into regs BEFORE compute (issue-early/write-late)
  {
    float acc[2][8];
#pragma unroll
    for (int si = 0; si < 2; ++si)
#pragma unroll
      for (int i = 0; i < 8; ++i) acc[si][i] = 0.f;

    float4* st4 = (float4*)buf;
    for (int ch = 0; ch < 8; ++ch) {
      if (ch) __syncthreads();             // previous chunk fully consumed
      st4[t] = r0; st4[256 + t] = r1; st4[512 + t] = r2; st4[768 + t] = r3;
      __syncthreads();
      if (ch < 7) {                        // prefetch next chunk; lands during
        const float4* Dx = D4 + (ch + 1) * 1024;   // the 8 c8-iterations below
        r0 = Dx[t]; r1 = Dx[256 + t]; r2 = Dx[512 + t]; r3 = Dx[768 + t];
      }
#pragma unroll
      for (int c8 = 0; c8 < 8; ++c8) {
        const int c = ch * 8 + c8;
        const float x0 = __shfl(xf0, c);
        const float x1 = __shfl(xf1, c);
        const float2* row2 = (const float2*)(buf + c8 * NA);
#pragma unroll
        for (int i = 0; i < 4; ++i) {
          float2 dv = row2[(i << 6) + lane];
          acc[0][i * 2] += x0 * dv.x; acc[0][i * 2 + 1] += x0 * dv.y;
          acc[1][i * 2] += x1 * dv.x; acc[1][i * 2 + 1] += x1 * dv.y;
        }
      }
    }
    __syncthreads();                       // all waves done reading stage
    // park h_bar into the same 16 KB (per-wave region); acc DIES here
    // (park layout is linear h_bar[sig][atom]: float2 idx i*64+lane ->
    //  atoms i*128+2*lane, +1 -- matches acc slot s <-> (s>>1)*128+2*lane+(s&1))
    float2* park2 = (float2*)buf;
#pragma unroll
    for (int si = 0; si < 2; ++si)
#pragma unroll
      for (int i = 0; i < 4; ++i) {
        float2 v; v.x = acc[si][i * 2]; v.y = acc[si][i * 2 + 1];
        park2[(size_t)(wv * 2 + si) * 256 + (i << 6) + lane] = v;
      }
  }

  // ---- phase 2: OMP, one signal per 32-lane half (wave-local park, no barrier)
  const float* parkS = buf + (size_t)sig * NA;
  float h16[16];
  {
    const float2* pk2 = (const float2*)parkS;
#pragma unroll
    for (int i = 0; i < 8; ++i) {          // h(0) = h_bar in half-mapping
      float2 hv = pk2[(i << 5) + hl];
      h16[i * 2] = hv.x; h16[i * 2 + 1] = hv.y;
    }
  }
  unsigned msk = 0xFFFFu;
  int I[KS];
  float Lo[10], rd[KS], gam[KS];

  omp_stepH<0>(hl, G, parkS, h16, msk, I, Lo, rd, gam);
  omp_stepH<1>(hl, G, parkS, h16, msk, I, Lo, rd, gam);
  omp_stepH<2>(hl, G, parkS, h16, msk, I, Lo, rd, gam);
  omp_stepH<3>(hl, G, parkS, h16, msk, I, Lo, rd, gam);
  omp_stepH<4>(hl, G, parkS, h16, msk, I, Lo, rd, gam);

  // ---- epilogue: this half's signal, channels hl and hl+32
  float rrA = 0.f, rrB = 0.f;
#pragma unroll
  for (int j = 0; j < KS; ++j) {
    const float* dr = DnT + (size_t)I[j] * NC;
    rrA += gam[j] * dr[hl];
    rrB += gam[j] * dr[hl + 32];
  }
  const float dA = rrA - xfa, dB = rrB - xfb;  // z_dl - z_e
  xsz[hl * 8 + sig]        = xfa + dA;         // zout[c][s]
  xsz[(hl + 32) * 8 + sig] = xfb + dB;
  double sq = (double)dA * (double)dA + (double)dB * (double)dB;
#pragma unroll
  for (int off = 1; off < 32; off <<= 1) sq += __shfl_xor(sq, off);
  if (hl == 0) wsq[sig] = sq;

  // support / coeffs: constant-index selection chains only
  if (hl < KS) {
    int   iv = I[0];
    float gv = gam[0];
    if (hl == 1) { iv = I[1]; gv = gam[1]; }
    if (hl == 2) { iv = I[2]; gv = gam[2]; }
    if (hl == 3) { iv = I[3]; gv = gam[3]; }
    if (hl == 4) { iv = I[4]; gv = gam[4]; }
    const int m = m0 + sig;
    out[OUT_SUP + (size_t)m * KS + hl] = (float)iv;
    out[OUT_COF + (size_t)m * KS + hl] = gv;
  }

  __syncthreads();
  // coalesced z_dl store from zout (xsz[c*8+s])
  for (int j = t; j < 8 * NC; j += 256) {
    int c = j >> 3, s = j & 7;
    out[zbase + (size_t)c * 4096 + s] = xsz[j];
  }
  if (t == 0) {
    double ssum = 0.0;
#pragma unroll
    for (int i = 0; i < 8; ++i) ssum += wsq[i];
    atomicAdd(accum, ssum);
  }
}

__global__ void final_kernel(const double* __restrict__ accum, float* __restrict__ out) {
  double mse = *accum / 2097152.0;
  out[OUT_LOSS] = (float)(mse + 0.25 * mse);
}

extern "C" void kernel_launch(void* const* d_in, const int* in_sizes, int n_in,
                              void* d_out, int out_size, void* d_ws, size_t ws_size,
                              hipStream_t stream) {
  const float* z_e = (const float*)d_in[0];
  const float* dic = (const float*)d_in[1];
  float* out = (float*)d_out;
  float* ws = (float*)d_ws;
  float* Dn   = ws + WS_DN;
  float* DnT  = ws + WS_DNT;
  float* G    = ws + WS_G;
  double* accu = (double*)(ws + WS_ACCF);

  hipLaunchKernelGGL(norm_kernel,  dim3(8),    dim3(64),  0, stream, dic, Dn, DnT);
  hipLaunchKernelGGL(gram_kernel,  dim3(NA),   dim3(NA),  0, stream, Dn, G, accu);
  hipLaunchKernelGGL(omp_kernel,   dim3(4096), dim3(256), 0, stream,
                     z_e, Dn, DnT, G, out, accu);
  hipLaunchKernelGGL(final_kernel, dim3(1),    dim3(1),   0, stream, accu, out);
}

// Round 5
// 152.262 us; speedup vs baseline: 1.5009x; 1.1269x over previous
//
#include <hip/hip_runtime.h>

#define NC 64      // channels / signal dim
#define NA 512     // dictionary atoms
#define KS 5       // sparsity

// ---- workspace layout in FLOATS (accum as double at 8B-aligned tail) ----
#define WS_DN   0        // Dn  [NC][NA]
#define WS_DNT  32768    // DnT [NA][NC]
#define WS_G    65536    // G   [NA][NA]
#define WS_ACCF 327680   // double accumulator lives here (byte off 1310720)

// out layout (FLOAT32): z_dl[2097152] | loss[1] | support[163840] | coeffs[163840]
#define OUT_LOSS 2097152
#define OUT_SUP  2097153
#define OUT_COF  2260993

__global__ void norm_kernel(const float* __restrict__ D, float* __restrict__ Dn,
                            float* __restrict__ DnT) {
  int n = blockIdx.x * 64 + threadIdx.x;
  float s = 0.f;
  for (int c = 0; c < NC; ++c) {
    float v = D[c * NA + n];
    s += v * v;
  }
  float den = fmaxf(sqrtf(s), 1e-10f);
  for (int c = 0; c < NC; ++c) {
    float v = D[c * NA + n] / den;      // f32 true division, mirrors ref
    Dn[c * NA + n]  = v;
    DnT[n * NC + c] = v;
  }
}

__global__ void gram_kernel(const float* __restrict__ Dn,
                            float* __restrict__ G, double* __restrict__ accum) {
  __shared__ float col[NC];
  int i = blockIdx.x, t = threadIdx.x;
  if (t < NC) col[t] = Dn[t * NA + i];
  if (i == 0 && t == 0) *accum = 0.0;
  __syncthreads();
  float s = 0.f;
#pragma unroll
  for (int c = 0; c < NC; ++c) s += col[c] * Dn[c * NA + t];
  G[(size_t)i * NA + t] = s;
}

// One OMP iteration, HALF-WAVE parallel (R4-proven: singular state, no spill).
// b128 atom mapping: half-lane hl owns 16 atoms, slot s (0..15) <->
//   a = (s>>2)*128 + 4*hl + (s&3)   (ascending in s -> first-occurrence
// tie-break preserved).  Park reload is hoisted to right after the argmax
// (h16 is dead there) so the LDS reads overlap the Gc-load/Cholesky chain.
// gam[] doubles as y[] in the solve (in-place; identical operations).
template<int KK>
__device__ __forceinline__ void omp_stepH(
    const int hl, const float* __restrict__ G,
    const float* __restrict__ parkS,
    float (&h16)[16], unsigned &msk, int (&I)[KS],
    float (&Lo)[10], float (&rd)[KS], float (&gam)[KS]) {
  // ---- argmax |h|*mask; ascending-atom scan, strict '>' = first-occurrence
  float bv = -1.f; int bn = 0;
#pragma unroll
  for (int s = 0; s < 16; ++s) {
    int a = ((s >> 2) << 7) + 4 * hl + (s & 3);
    float v = ((msk >> s) & 1u) ? fabsf(h16[s]) : 0.f;
    if (v > bv) { bv = v; bn = a; }
  }
#pragma unroll
  for (int off = 1; off < 32; off <<= 1) {   // within-half butterfly
    float ov = __shfl_xor(bv, off);
    int   on = __shfl_xor(bn, off);
    if (ov > bv || (ov == bv && on < bn)) { bv = ov; bn = on; }
  }
  const int idx = bn;                        // half-uniform
  if (((idx & 127) >> 2) == hl)
    msk &= ~(1u << (((idx >> 7) << 2) | (idx & 3)));
  I[KK] = idx;

  // ---- EARLY park reload: h16 = h_bar (dead after argmax; LDS latency
  // overlaps the global Gc loads + Cholesky below; park is immutable)
  if constexpr (KK < 4) {
    const float4* pk4 = (const float4*)parkS;
#pragma unroll
    for (int i = 0; i < 4; ++i) {
      float4 hv = pk4[(i << 5) + hl];
      h16[i*4+0] = hv.x; h16[i*4+1] = hv.y; h16[i*4+2] = hv.z; h16[i*4+3] = hv.w;
    }
  }

  // ---- Cholesky rank-1 extension (replicated within the half)
  if constexpr (KK == 0) {
    rd[0] = 1.f;
  } else {
    float Gc[KK], w_[KK];
#pragma unroll
    for (int j = 0; j < KK; ++j) Gc[j] = G[(size_t)I[j] * NA + idx];
#pragma unroll
    for (int i = 0; i < KK; ++i) {
      float ssum = Gc[i];
#pragma unroll
      for (int j = 0; j < i; ++j) ssum -= Lo[i*(i-1)/2 + j] * w_[j];
      w_[i] = ssum * rd[i];
    }
    float ww = 0.f;
#pragma unroll
    for (int i = 0; i < KK; ++i) ww += w_[i] * w_[i];
    float corner = sqrtf(fmaxf(1.f - ww, 1e-12f));
#pragma unroll
    for (int j = 0; j < KK; ++j) Lo[KK*(KK-1)/2 + j] = w_[j];
    rd[KK] = 1.f / corner;
  }

  // ---- cho_solve((L, lower), h_bar[I]) at size KK+1, in-place in gam
  // (park broadcast reads; forward solve leaves y in gam, backward finalizes)
#pragma unroll
  for (int i = 0; i <= KK; ++i) {
    float b_ = parkS[I[i]];
#pragma unroll
    for (int j = 0; j < i; ++j) b_ -= Lo[i*(i-1)/2 + j] * gam[j];
    gam[i] = b_ * rd[i];
  }
#pragma unroll
  for (int i = KK; i >= 0; --i) {
    float g_ = gam[i];
#pragma unroll
    for (int j = i + 1; j <= KK; ++j) g_ -= Lo[j*(j-1)/2 + i] * gam[j];
    gam[i] = g_ * rd[i];
  }

  // ---- h refresh: h = h_bar - sum_j gam_j * G[I_j]  (b128 global rows)
  if constexpr (KK < 4) {
#pragma unroll
    for (int j = 0; j <= KK; ++j) {
      const float4* g4 = (const float4*)(G + (size_t)I[j] * NA);
      const float gj = gam[j];
#pragma unroll
      for (int i = 0; i < 4; ++i) {
        float4 g = g4[(i << 5) + hl];
        h16[i*4+0] -= gj * g.x; h16[i*4+1] -= gj * g.y;
        h16[i*4+2] -= gj * g.z; h16[i*4+3] -= gj * g.w;
      }
    }
  }
}

// 8 signals per block (2 per wave in phase 2, one per 32-lane HALF), grid 4096.
// PHASE 1 IS LDS-FREE (R4 post-mortem: the Dn LDS stage was ~26K LDS
// wave-instrs/CU on the single per-CU LDS unit -- the real phase-1 floor).
// Each wave owns a 128-atom slice for ALL 8 signals: Dn streams global->reg
// coalesced (L2-resident); x[s][c] is wave-uniform so it comes from z via
// uniform (scalar-pipe) loads.  Per-(sig,atom) accumulation stays ascending-c
// in one thread -> h_bar bit-identical to R4's.  17 barriers -> 3.
// LDS: 16 KB park + 2 KB xsz -> ~18.4 KB.
__global__ __launch_bounds__(256, 2) void omp_kernel(
    const float* __restrict__ z, const float* __restrict__ Dn,
    const float* __restrict__ DnT, const float* __restrict__ G,
    float* __restrict__ out, double* __restrict__ accum) {
  __shared__ __align__(16) float park[8 * NA];  // 16 KB h_bar park
  __shared__ float xsz[8 * NC];      // 2 KB: xs[s][c] first, zout[c][s] later
  __shared__ double wsq[8];
  const int t = threadIdx.x, lane = t & 63, wv = t >> 6;
  const int hl = lane & 31;
  const int m0 = blockIdx.x * 8;
  const int bh = m0 >> 6, b = bh >> 6, h = bh & 63, w0 = m0 & 63;
  const size_t zbase = (size_t)b * 262144 + (size_t)h * 64 + w0;

  // load 8 signals coalesced into xs (xsz[s*64+c]) -- epilogue x + zout reuse
  for (int j = t; j < 8 * NC; j += 256) {
    int c = j >> 3, s = j & 7;
    xsz[s * NC + c] = z[zbase + (size_t)c * 4096 + s];
  }
  __syncthreads();
  // this half's signal; epilogue channels 2*hl, 2*hl+1 (float2-friendly)
  const int sig = wv * 2 + (lane >> 5);
  const float2 xf2 = *(const float2*)&xsz[sig * NC + 2 * hl];
  // xsz free from here (zout reuses it)

  // ---- phase 1: LDS-free h_bar GEMM.  Wave wv owns atoms [wv*128, wv*128+128),
  // lane owns the float2 pair (2*lane, 2*lane+1) within the slice, for all 8
  // signals.  x comes from z via wave-uniform loads (scalar pipe).
  {
    float acc[8][2];
#pragma unroll
    for (int s = 0; s < 8; ++s) { acc[s][0] = 0.f; acc[s][1] = 0.f; }

    const float2* Dn2 = (const float2*)Dn + (wv << 6) + lane;  // + c*256 per ch
    const float4* zp4 = (const float4*)(z + zbase);            // uniform base
#pragma unroll 8
    for (int c = 0; c < 64; ++c) {
      float2 dv = Dn2[c << 8];             // Dn[c][wv*128 + 2*lane + {0,1}]
      float4 xa = zp4[(c << 10)];          // x[0..3][c]  (uniform -> s_load)
      float4 xb = zp4[(c << 10) + 1];      // x[4..7][c]
      acc[0][0] += xa.x * dv.x; acc[0][1] += xa.x * dv.y;
      acc[1][0] += xa.y * dv.x; acc[1][1] += xa.y * dv.y;
      acc[2][0] += xa.z * dv.x; acc[2][1] += xa.z * dv.y;
      acc[3][0] += xa.w * dv.x; acc[3][1] += xa.w * dv.y;
      acc[4][0] += xb.x * dv.x; acc[4][1] += xb.x * dv.y;
      acc[5][0] += xb.y * dv.x; acc[5][1] += xb.y * dv.y;
      acc[6][0] += xb.z * dv.x; acc[6][1] += xb.z * dv.y;
      acc[7][0] += xb.w * dv.x; acc[7][1] += xb.w * dv.y;
    }
    // park h_bar[sig][atom] (each wave writes its 128-atom slice of all 8)
    float2* park2 = (float2*)park;
#pragma unroll
    for (int s = 0; s < 8; ++s)
      park2[(s << 8) + (wv << 6) + lane] = make_float2(acc[s][0], acc[s][1]);
  }
  __syncthreads();                         // park complete (all waves)

  // ---- phase 2: OMP, one signal per 32-lane half
  const float* parkS = park + (size_t)sig * NA;
  float h16[16];
  {
    const float4* pk4 = (const float4*)parkS;
#pragma unroll
    for (int i = 0; i < 4; ++i) {          // h(0) = h_bar in b128 half-mapping
      float4 hv = pk4[(i << 5) + hl];
      h16[i*4+0] = hv.x; h16[i*4+1] = hv.y; h16[i*4+2] = hv.z; h16[i*4+3] = hv.w;
    }
  }
  unsigned msk = 0xFFFFu;
  int I[KS];
  float Lo[10], rd[KS], gam[KS];

  omp_stepH<0>(hl, G, parkS, h16, msk, I, Lo, rd, gam);
  omp_stepH<1>(hl, G, parkS, h16, msk, I, Lo, rd, gam);
  omp_stepH<2>(hl, G, parkS, h16, msk, I, Lo, rd, gam);
  omp_stepH<3>(hl, G, parkS, h16, msk, I, Lo, rd, gam);
  omp_stepH<4>(hl, G, parkS, h16, msk, I, Lo, rd, gam);

  // ---- epilogue: this half's signal, channels 2*hl and 2*hl+1
  float rrA = 0.f, rrB = 0.f;
#pragma unroll
  for (int j = 0; j < KS; ++j) {
    const float2 dvv = ((const float2*)(DnT + (size_t)I[j] * NC))[hl];
    rrA += gam[j] * dvv.x;
    rrB += gam[j] * dvv.y;
  }
  const float dA = rrA - xf2.x, dB = rrB - xf2.y;  // z_dl - z_e
  xsz[(2 * hl) * 8 + sig]     = xf2.x + dA;        // zout[c][s]
  xsz[(2 * hl + 1) * 8 + sig] = xf2.y + dB;
  double sq = (double)dA * (double)dA + (double)dB * (double)dB;
#pragma unroll
  for (int off = 1; off < 32; off <<= 1) sq += __shfl_xor(sq, off);
  if (hl == 0) wsq[sig] = sq;

  // support / coeffs: constant-index selection chains only
  if (hl < KS) {
    int   iv = I[0];
    float gv = gam[0];
    if (hl == 1) { iv = I[1]; gv = gam[1]; }
    if (hl == 2) { iv = I[2]; gv = gam[2]; }
    if (hl == 3) { iv = I[3]; gv = gam[3]; }
    if (hl == 4) { iv = I[4]; gv = gam[4]; }
    const int m = m0 + sig;
    out[OUT_SUP + (size_t)m * KS + hl] = (float)iv;
    out[OUT_COF + (size_t)m * KS + hl] = gv;
  }

  __syncthreads();
  // coalesced z_dl store from zout (xsz[c*8+s])
  for (int j = t; j < 8 * NC; j += 256) {
    int c = j >> 3, s = j & 7;
    out[zbase + (size_t)c * 4096 + s] = xsz[j];
  }
  if (t == 0) {
    double ssum = 0.0;
#pragma unroll
    for (int i = 0; i < 8; ++i) ssum += wsq[i];
    atomicAdd(accum, ssum);
  }
}

__global__ void final_kernel(const double* __restrict__ accum, float* __restrict__ out) {
  double mse = *accum / 2097152.0;
  out[OUT_LOSS] = (float)(mse + 0.25 * mse);
}

extern "C" void kernel_launch(void* const* d_in, const int* in_sizes, int n_in,
                              void* d_out, int out_size, void* d_ws, size_t ws_size,
                              hipStream_t stream) {
  const float* z_e = (const float*)d_in[0];
  const float* dic = (const float*)d_in[1];
  float* out = (float*)d_out;
  float* ws = (float*)d_ws;
  float* Dn   = ws + WS_DN;
  float* DnT  = ws + WS_DNT;
  float* G    = ws + WS_G;
  double* accu = (double*)(ws + WS_ACCF);

  hipLaunchKernelGGL(norm_kernel,  dim3(8),    dim3(64),  0, stream, dic, Dn, DnT);
  hipLaunchKernelGGL(gram_kernel,  dim3(NA),   dim3(NA),  0, stream, Dn, G, accu);
  hipLaunchKernelGGL(omp_kernel,   dim3(4096), dim3(256), 0, stream,
                     z_e, Dn, DnT, G, out, accu);
  hipLaunchKernelGGL(final_kernel, dim3(1),    dim3(1),   0, stream, accu, out);
}